// Round 6
// baseline (1907.239 us; speedup 1.0000x reference)
//
#include <hip/hip_runtime.h>

#define N_NODES 50000
#define N_EDGES 800000
#define C_IN 64
#define HID 3
#define C_OUTC 128
#define ATTR 6
#define K3 192            // HID*C_IN
#define NBK 782           // buckets of 64 nodes (dst>>6)
#define CAP 1280          // per-bucket capacity: mean 1023, +8 sigma
#define EPB 4096          // edges per pass1 block
#define P1B 196           // pass1 blocks per layer (196*4096 >= 800000)

// ---------------------------------------------------------------------------
// pass1: bin edges by bucket (dst>>6) for BOTH layers. LDS staging groups
// each block's edges by bucket so global writes are coalesced runs; one
// global atomic per (block,bucket) reserves segment space. Payload packed as
// {eid | dstlocal<<20, src} (eid < 2^20, dstlocal < 64).
// ---------------------------------------------------------------------------
__global__ __launch_bounds__(512)
void pass1(const int* __restrict__ ei0, const int* __restrict__ ei1,
           int* __restrict__ cursor, int2* __restrict__ seg)
{
    __shared__ int s_cnt[NBK], s_ofs[NBK], s_pos[NBK], s_gbase[NBK]; // 12.5 KB
    __shared__ int2 st_es[EPB];                                      // 32 KB
    __shared__ unsigned short st_b[EPB];                             //  8 KB
    __shared__ int wsum[8];
    const int t = threadIdx.x, lane = t & 63, wid = t >> 6;
    const int l = (blockIdx.x >= P1B) ? 1 : 0;
    const int* ei = l ? ei1 : ei0;
    const int base = (blockIdx.x - l * P1B) * EPB;

    for (int i = t; i < NBK; i += 512) s_cnt[i] = 0;
    __syncthreads();

    int src[8], dst[8];
    const int e0 = base + t * 8;
    if (e0 + 7 < N_EDGES) {
        const int4 s0 = *(const int4*)(ei + e0);
        const int4 s1 = *(const int4*)(ei + e0 + 4);
        const int4 d0 = *(const int4*)(ei + N_EDGES + e0);
        const int4 d1 = *(const int4*)(ei + N_EDGES + e0 + 4);
        src[0]=s0.x; src[1]=s0.y; src[2]=s0.z; src[3]=s0.w;
        src[4]=s1.x; src[5]=s1.y; src[6]=s1.z; src[7]=s1.w;
        dst[0]=d0.x; dst[1]=d0.y; dst[2]=d0.z; dst[3]=d0.w;
        dst[4]=d1.x; dst[5]=d1.y; dst[6]=d1.z; dst[7]=d1.w;
    } else {
#pragma unroll
        for (int j = 0; j < 8; ++j) {
            const int e = e0 + j;
            if (e < N_EDGES) { src[j] = ei[e]; dst[j] = ei[N_EDGES + e]; }
            else dst[j] = -1;
        }
    }
#pragma unroll
    for (int j = 0; j < 8; ++j)
        if (dst[j] >= 0) atomicAdd(&s_cnt[dst[j] >> 6], 1);
    __syncthreads();

    // Exclusive block scan of s_cnt[NBK], 2 elements per thread.
    const int i0 = 2 * t, i1 = 2 * t + 1;
    const int v0 = (i0 < NBK) ? s_cnt[i0] : 0;
    const int v1 = (i1 < NBK) ? s_cnt[i1] : 0;
    const int pv = v0 + v1;
    int incl = pv;
#pragma unroll
    for (int off = 1; off < 64; off <<= 1) {
        const int u = __shfl_up(incl, off, 64);
        if (lane >= off) incl += u;
    }
    if (lane == 63) wsum[wid] = incl;
    __syncthreads();
    if (wid == 0) {
        int s = (lane < 8) ? wsum[lane] : 0;
#pragma unroll
        for (int off = 1; off < 8; off <<= 1) {
            const int u = __shfl_up(s, off, 64);
            if (lane >= off) s += u;
        }
        if (lane < 8) wsum[lane] = s;            // inclusive wave sums
    }
    __syncthreads();
    const int ex = (wid ? wsum[wid - 1] : 0) + (incl - pv);
    if (i0 < NBK) { s_ofs[i0] = ex;      s_pos[i0] = ex; }
    if (i1 < NBK) { s_ofs[i1] = ex + v0; s_pos[i1] = ex + v0; }
    __syncthreads();

    // Reserve global segment space (one atomic per bucket per block).
    for (int i = t; i < NBK; i += 512)
        s_gbase[i] = atomicAdd(&cursor[(l << 10) + i], s_cnt[i]);

    // Place into LDS stage, grouped by bucket.
#pragma unroll
    for (int j = 0; j < 8; ++j) {
        if (dst[j] >= 0) {
            const int b = dst[j] >> 6;
            const int p = atomicAdd(&s_pos[b], 1);
            st_es[p] = make_int2((e0 + j) | ((dst[j] & 63) << 20), src[j]);
            st_b[p]  = (unsigned short)b;
        }
    }
    __syncthreads();

    // Coalesced write-out of bucket runs.
    const int total = (N_EDGES - base < EPB) ? (N_EDGES - base) : EPB;
    for (int j = t; j < total; j += 512) {
        const int b = st_b[j];
        const int g = s_gbase[b] + (j - s_ofs[b]);
        if (g < CAP) seg[(size_t)(l * NBK + b) * CAP + g] = st_es[j];
    }
}

// ---------------------------------------------------------------------------
// mega: one block per (layer, bucket of 64 nodes). Phase B: stream the
// bucket's edges, wave-per-edge, MLP in regs, accumulate into the 48 KB LDS
// aggr tile via ds_add_f32 (stride-3 => 2 lanes/bank = free). Phase C: GEMM
// [64,192]@[192,128] straight from LDS + bias + tanh + coalesced store.
// Replaces pass2 + gather + node kernels and the aggr HBM round-trip.
// ---------------------------------------------------------------------------
__global__ __launch_bounds__(512)
void mega(const float* __restrict__ x,
          const float* __restrict__ ea0, const float* __restrict__ ea1,
          const float* __restrict__ Wi0, const float* __restrict__ bi0,
          const float* __restrict__ Wo0, const float* __restrict__ bo0,
          const float* __restrict__ Wi1, const float* __restrict__ bi1,
          const float* __restrict__ Wo1, const float* __restrict__ bo1,
          const int* __restrict__ cursor, const int2* __restrict__ seg,
          float* __restrict__ out)
{
    __shared__ float agg[64 * K3];                  // 48 KB
    const int t = threadIdx.x, lane = t & 63, wv = t >> 6;
    const int l = (blockIdx.x >= NBK) ? 1 : 0;
    const int b = blockIdx.x - l * NBK;
    const float* ea = l ? ea1 : ea0;
    const float* Wi = l ? Wi1 : Wi0;
    const float* bi = l ? bi1 : bi0;
    const float* Wo = l ? Wo1 : Wo0;
    const float* bo = l ? bo1 : bo0;

    for (int i = t; i < 64 * K3; i += 512) agg[i] = 0.f;

    const int col = 3 * lane;
    float w[ATTR][HID], bb[HID];
#pragma unroll
    for (int k = 0; k < ATTR; ++k)
#pragma unroll
        for (int h = 0; h < HID; ++h)
            w[k][h] = Wi[k * K3 + col + h];
#pragma unroll
    for (int h = 0; h < HID; ++h) bb[h] = bi[col + h];
    __syncthreads();

    const int S0 = cursor[(l << 10) + b];
    const int S  = (S0 < CAP) ? S0 : CAP;
    const int2* segb = seg + (size_t)(l * NBK + b) * CAP;

    // Phase B: edges, 8 waves round-robin, unroll 4 (4 memory chains/wave).
    for (int i = wv * 4; i < S; i += 32) {
        int2 p[4]; float2 a01[4], a23[4], a45[4]; float xj[4];
#pragma unroll
        for (int j = 0; j < 4; ++j) {
            const int idx = (i + j < S) ? i + j : i;    // clamp: valid dup
            p[j] = segb[idx];
        }
#pragma unroll
        for (int j = 0; j < 4; ++j) {
            const int eid = p[j].x & 0xFFFFF;
            const float* eap = ea + (size_t)eid * ATTR;
            a01[j] = *(const float2*)(eap + 0);
            a23[j] = *(const float2*)(eap + 2);
            a45[j] = *(const float2*)(eap + 4);
            const float xv = x[(size_t)(unsigned)p[j].y * C_IN + lane];
            xj[j] = (i + j < S) ? xv : 0.f;             // dup edges -> 0
        }
#pragma unroll
        for (int j = 0; j < 4; ++j) {
            const int dl = p[j].x >> 20;                // 0..63
            float s0 = bb[0], s1 = bb[1], s2 = bb[2];
            s0 = fmaf(a01[j].x, w[0][0], s0); s1 = fmaf(a01[j].x, w[0][1], s1); s2 = fmaf(a01[j].x, w[0][2], s2);
            s0 = fmaf(a01[j].y, w[1][0], s0); s1 = fmaf(a01[j].y, w[1][1], s1); s2 = fmaf(a01[j].y, w[1][2], s2);
            s0 = fmaf(a23[j].x, w[2][0], s0); s1 = fmaf(a23[j].x, w[2][1], s1); s2 = fmaf(a23[j].x, w[2][2], s2);
            s0 = fmaf(a23[j].y, w[3][0], s0); s1 = fmaf(a23[j].y, w[3][1], s1); s2 = fmaf(a23[j].y, w[3][2], s2);
            s0 = fmaf(a45[j].x, w[4][0], s0); s1 = fmaf(a45[j].x, w[4][1], s1); s2 = fmaf(a45[j].x, w[4][2], s2);
            s0 = fmaf(a45[j].y, w[5][0], s0); s1 = fmaf(a45[j].y, w[5][1], s1); s2 = fmaf(a45[j].y, w[5][2], s2);
            float* ap = &agg[dl * K3 + col];
            atomicAdd(ap + 0, fmaxf(s0, 0.f) * xj[j]);
            atomicAdd(ap + 1, fmaxf(s1, 0.f) * xj[j]);
            atomicAdd(ap + 2, fmaxf(s2, 0.f) * xj[j]);
        }
    }
    __syncthreads();

    // Phase C: GEMM from LDS. thread = 4 nodes x 4 outs; k-step 4 (b128 LDS).
    const int o4 = (t & 31) * 4;
    const int g4 = (t >> 5) * 4;                        // 0..60
    float acc[4][4];
#pragma unroll
    for (int i = 0; i < 4; ++i)
#pragma unroll
        for (int j = 0; j < 4; ++j) acc[i][j] = 0.f;

    for (int k = 0; k < K3; k += 4) {
        const float4 w0 = *(const float4*)(Wo + (size_t)(k + 0) * C_OUTC + o4);
        const float4 w1 = *(const float4*)(Wo + (size_t)(k + 1) * C_OUTC + o4);
        const float4 w2 = *(const float4*)(Wo + (size_t)(k + 2) * C_OUTC + o4);
        const float4 w3 = *(const float4*)(Wo + (size_t)(k + 3) * C_OUTC + o4);
#pragma unroll
        for (int i = 0; i < 4; ++i) {
            const float4 av = *(const float4*)(&agg[(g4 + i) * K3 + k]);
            acc[i][0] = fmaf(av.x, w0.x, acc[i][0]);
            acc[i][1] = fmaf(av.x, w0.y, acc[i][1]);
            acc[i][2] = fmaf(av.x, w0.z, acc[i][2]);
            acc[i][3] = fmaf(av.x, w0.w, acc[i][3]);
            acc[i][0] = fmaf(av.y, w1.x, acc[i][0]);
            acc[i][1] = fmaf(av.y, w1.y, acc[i][1]);
            acc[i][2] = fmaf(av.y, w1.z, acc[i][2]);
            acc[i][3] = fmaf(av.y, w1.w, acc[i][3]);
            acc[i][0] = fmaf(av.z, w2.x, acc[i][0]);
            acc[i][1] = fmaf(av.z, w2.y, acc[i][1]);
            acc[i][2] = fmaf(av.z, w2.z, acc[i][2]);
            acc[i][3] = fmaf(av.z, w2.w, acc[i][3]);
            acc[i][0] = fmaf(av.w, w3.x, acc[i][0]);
            acc[i][1] = fmaf(av.w, w3.y, acc[i][1]);
            acc[i][2] = fmaf(av.w, w3.z, acc[i][2]);
            acc[i][3] = fmaf(av.w, w3.w, acc[i][3]);
        }
    }

    const float4 bias = *(const float4*)(bo + o4);
#pragma unroll
    for (int i = 0; i < 4; ++i) {
        const int node = b * 64 + g4 + i;
        if (node < N_NODES) {
            float4 r;
            r.x = tanhf(acc[i][0] + bias.x);
            r.y = tanhf(acc[i][1] + bias.y);
            r.z = tanhf(acc[i][2] + bias.z);
            r.w = tanhf(acc[i][3] + bias.w);
            *(float4*)(out + (size_t)node * (2 * C_OUTC) + l * C_OUTC + o4) = r;
        }
    }
}

extern "C" void kernel_launch(void* const* d_in, const int* in_sizes, int n_in,
                              void* d_out, int out_size, void* d_ws, size_t ws_size,
                              hipStream_t stream) {
    const float* x   = (const float*)d_in[0];
    const int*   ei0 = (const int*)d_in[1];
    const int*   ei1 = (const int*)d_in[3];
    const float* ea0 = (const float*)d_in[2];
    const float* ea1 = (const float*)d_in[4];
    const float* Wi0 = (const float*)d_in[5];
    const float* bi0 = (const float*)d_in[6];
    const float* Wo0 = (const float*)d_in[7];
    const float* bo0 = (const float*)d_in[8];
    const float* Wi1 = (const float*)d_in[9];
    const float* bi1 = (const float*)d_in[10];
    const float* Wo1 = (const float*)d_in[11];
    const float* bo1 = (const float*)d_in[12];
    float* out = (float*)d_out;

    // Workspace: cursor 2048 ints (8 KB, stride 1024/layer) + seg 16.0 MB.
    int*  cursor = (int*)d_ws;
    int2* seg    = (int2*)(cursor + 2048);

    hipMemsetAsync(cursor, 0, 2048 * sizeof(int), stream);
    pass1<<<2 * P1B, 512, 0, stream>>>(ei0, ei1, cursor, seg);
    mega<<<2 * NBK, 512, 0, stream>>>(x, ea0, ea1,
                                      Wi0, bi0, Wo0, bo0,
                                      Wi1, bi1, Wo1, bo1,
                                      cursor, seg, out);
}

// Round 7
// 432.261 us; speedup vs baseline: 4.4122x; 4.4122x over previous
//
#include <hip/hip_runtime.h>

#define N_NODES 50000
#define N_EDGES 800000
#define C_IN 64
#define HID 3
#define C_OUTC 128
#define ATTR 6
#define K3 192            // HID*C_IN
#define NBK 782           // fine buckets of 64 nodes (dst>>6)
#define NPAD 50048        // NBK*64
#define CAP 1280          // per-bucket capacity: mean 1023, +8 sigma
#define EPB 4096          // edges per pass1 block
#define P1B 196           // pass1 blocks per layer

// ---------------------------------------------------------------------------
// pass1: bin edges by fine bucket (dst>>6), both layers. LDS staging groups
// each block's edges by bucket -> coalesced global segment writes; one global
// int atomic per (block,bucket). Payload {eid | dstlocal<<20, src}.
// (Unchanged from R6 — it was not the regression.)
// ---------------------------------------------------------------------------
__global__ __launch_bounds__(512)
void pass1(const int* __restrict__ ei0, const int* __restrict__ ei1,
           int* __restrict__ cursor, int2* __restrict__ seg)
{
    __shared__ int s_cnt[NBK], s_ofs[NBK], s_pos[NBK], s_gbase[NBK]; // 12.5 KB
    __shared__ int2 st_es[EPB];                                      // 32 KB
    __shared__ unsigned short st_b[EPB];                             //  8 KB
    __shared__ int wsum[8];
    const int t = threadIdx.x, lane = t & 63, wid = t >> 6;
    const int l = (blockIdx.x >= P1B) ? 1 : 0;
    const int* ei = l ? ei1 : ei0;
    const int base = (blockIdx.x - l * P1B) * EPB;

    for (int i = t; i < NBK; i += 512) s_cnt[i] = 0;
    __syncthreads();

    int src[8], dst[8];
    const int e0 = base + t * 8;
    if (e0 + 7 < N_EDGES) {
        const int4 s0 = *(const int4*)(ei + e0);
        const int4 s1 = *(const int4*)(ei + e0 + 4);
        const int4 d0 = *(const int4*)(ei + N_EDGES + e0);
        const int4 d1 = *(const int4*)(ei + N_EDGES + e0 + 4);
        src[0]=s0.x; src[1]=s0.y; src[2]=s0.z; src[3]=s0.w;
        src[4]=s1.x; src[5]=s1.y; src[6]=s1.z; src[7]=s1.w;
        dst[0]=d0.x; dst[1]=d0.y; dst[2]=d0.z; dst[3]=d0.w;
        dst[4]=d1.x; dst[5]=d1.y; dst[6]=d1.z; dst[7]=d1.w;
    } else {
#pragma unroll
        for (int j = 0; j < 8; ++j) {
            const int e = e0 + j;
            if (e < N_EDGES) { src[j] = ei[e]; dst[j] = ei[N_EDGES + e]; }
            else dst[j] = -1;
        }
    }
#pragma unroll
    for (int j = 0; j < 8; ++j)
        if (dst[j] >= 0) atomicAdd(&s_cnt[dst[j] >> 6], 1);   // int: native
    __syncthreads();

    // Exclusive block scan of s_cnt[NBK], 2 elements per thread.
    const int i0 = 2 * t, i1 = 2 * t + 1;
    const int v0 = (i0 < NBK) ? s_cnt[i0] : 0;
    const int v1 = (i1 < NBK) ? s_cnt[i1] : 0;
    const int pv = v0 + v1;
    int incl = pv;
#pragma unroll
    for (int off = 1; off < 64; off <<= 1) {
        const int u = __shfl_up(incl, off, 64);
        if (lane >= off) incl += u;
    }
    if (lane == 63) wsum[wid] = incl;
    __syncthreads();
    if (wid == 0) {
        int s = (lane < 8) ? wsum[lane] : 0;
#pragma unroll
        for (int off = 1; off < 8; off <<= 1) {
            const int u = __shfl_up(s, off, 64);
            if (lane >= off) s += u;
        }
        if (lane < 8) wsum[lane] = s;
    }
    __syncthreads();
    const int ex = (wid ? wsum[wid - 1] : 0) + (incl - pv);
    if (i0 < NBK) { s_ofs[i0] = ex;      s_pos[i0] = ex; }
    if (i1 < NBK) { s_ofs[i1] = ex + v0; s_pos[i1] = ex + v0; }
    __syncthreads();

    for (int i = t; i < NBK; i += 512)
        s_gbase[i] = atomicAdd(&cursor[(l << 10) + i], s_cnt[i]);

#pragma unroll
    for (int j = 0; j < 8; ++j) {
        if (dst[j] >= 0) {
            const int b = dst[j] >> 6;
            const int p = atomicAdd(&s_pos[b], 1);            // int: native
            st_es[p] = make_int2((e0 + j) | ((dst[j] & 63) << 20), src[j]);
            st_b[p]  = (unsigned short)b;
        }
    }
    __syncthreads();

    const int total = (N_EDGES - base < EPB) ? (N_EDGES - base) : EPB;
    for (int j = t; j < total; j += 512) {
        const int b = st_b[j];
        const int g = s_gbase[b] + (j - s_ofs[b]);
        if (g < CAP) seg[(size_t)(l * NBK + b) * CAP + g] = st_es[j];
    }
}

// ---------------------------------------------------------------------------
// pass2: one block per (layer, fine bucket). Int-LDS histogram over the 64
// local nodes -> wave scan -> scatter entries node-sorted into the bucket's
// own padded csr region (block-owned 10 KB => write-amp ~1) + row_info.
// ---------------------------------------------------------------------------
__global__ __launch_bounds__(256)
void pass2(const int* __restrict__ cursor, const int2* __restrict__ seg,
           int2* __restrict__ csr, int2* __restrict__ row_info)
{
    __shared__ int hist[64], cur[64];
    const int t = threadIdx.x;
    const int l = (blockIdx.x >= NBK) ? 1 : 0;
    const int fb = blockIdx.x - l * NBK;
    const int S0 = cursor[(l << 10) + fb];
    const int S = (S0 < CAP) ? S0 : CAP;
    const size_t base = (size_t)(l * NBK + fb) * CAP;
    const int2* segb = seg + base;

    if (t < 64) hist[t] = 0;
    __syncthreads();
    for (int i = t; i < S; i += 256)
        atomicAdd(&hist[(segb[i].x >> 20) & 63], 1);          // int: native
    __syncthreads();

    if (t < 64) {                                             // wave 0 scan
        const int v = hist[t];
        int incl = v;
#pragma unroll
        for (int off = 1; off < 64; off <<= 1) {
            const int u = __shfl_up(incl, off, 64);
            if (t >= off) incl += u;
        }
        const int excl = incl - v;
        cur[t] = excl;
        const int node = fb * 64 + t;
        if (node < N_NODES)
            row_info[l * NPAD + node] = make_int2((int)base + excl, v);
    }
    __syncthreads();

    for (int i = t; i < S; i += 256) {
        const int2 p = segb[i];
        const int dl = (p.x >> 20) & 63;
        const int pos = atomicAdd(&cur[dl], 1);               // int: native
        csr[base + pos] = p;
    }
}

// ---------------------------------------------------------------------------
// xcvt: x fp32 -> bf16 (round-to-nearest-even). 3.2M elements.
// ---------------------------------------------------------------------------
__global__ __launch_bounds__(256)
void xcvt(const float* __restrict__ x, unsigned short* __restrict__ xb)
{
    const int i = blockIdx.x * 256 + threadIdx.x;             // float4 index
    if (i < (N_NODES * C_IN) / 4) {
        const float4 v = ((const float4*)x)[i];
        ushort4 o;
        unsigned u;
        u = __float_as_uint(v.x); o.x = (unsigned short)((u + 0x7FFF + ((u >> 16) & 1)) >> 16);
        u = __float_as_uint(v.y); o.y = (unsigned short)((u + 0x7FFF + ((u >> 16) & 1)) >> 16);
        u = __float_as_uint(v.z); o.z = (unsigned short)((u + 0x7FFF + ((u >> 16) & 1)) >> 16);
        u = __float_as_uint(v.w); o.w = (unsigned short)((u + 0x7FFF + ((u >> 16) & 1)) >> 16);
        ((ushort4*)xb)[i] = o;
    }
}

// ---------------------------------------------------------------------------
// mega: one block per (layer, bucket of 64 nodes). Phase B: wave-per-node
// register gather over the node's sorted csr run (unroll-4), bf16 x row
// (128 B = 1 line/edge). Finished rows written to LDS with PLAIN stores
// (each row owned by exactly one wave -> no atomics). Phase C: GEMM
// [64,192]@[192,128] from LDS + bias + tanh + coalesced store.
// ---------------------------------------------------------------------------
__global__ __launch_bounds__(512)
void mega(const unsigned short* __restrict__ xb,
          const float* __restrict__ ea0, const float* __restrict__ ea1,
          const float* __restrict__ Wi0, const float* __restrict__ bi0,
          const float* __restrict__ Wo0, const float* __restrict__ bo0,
          const float* __restrict__ Wi1, const float* __restrict__ bi1,
          const float* __restrict__ Wo1, const float* __restrict__ bo1,
          const int2* __restrict__ row_info, const int2* __restrict__ csr,
          float* __restrict__ out)
{
    __shared__ float agg[64 * K3];                  // 48 KB
    const int t = threadIdx.x, lane = t & 63, wv = t >> 6;
    const int l = (blockIdx.x >= NBK) ? 1 : 0;
    const int b = blockIdx.x - l * NBK;
    const float* ea = l ? ea1 : ea0;
    const float* Wi = l ? Wi1 : Wi0;
    const float* bi = l ? bi1 : bi0;
    const float* Wo = l ? Wo1 : Wo0;
    const float* bo = l ? bo1 : bo0;

    const int col = 3 * lane;
    float w[ATTR][HID], bb[HID];
#pragma unroll
    for (int k = 0; k < ATTR; ++k)
#pragma unroll
        for (int h = 0; h < HID; ++h)
            w[k][h] = Wi[k * K3 + col + h];
#pragma unroll
    for (int h = 0; h < HID; ++h) bb[h] = bi[col + h];

    // Phase B: wave wv owns local nodes wv, wv+8, ..., wv+56.
    for (int dl = wv; dl < 64; dl += 8) {
        const int node = b * 64 + dl;
        int2 ri = make_int2(0, 0);
        if (node < N_NODES) ri = row_info[l * NPAD + node];
        const int2* ep = csr + ri.x;
        const int cnt = ri.y;

        float acc0 = 0.f, acc1 = 0.f, acc2 = 0.f;
        for (int i = 0; i < cnt; i += 4) {
            int2 p[4]; float2 a01[4], a23[4], a45[4]; float xj[4];
#pragma unroll
            for (int j = 0; j < 4; ++j) {
                const int idx = (i + j < cnt) ? i + j : cnt - 1;  // clamp dup
                p[j] = ep[idx];
            }
#pragma unroll
            for (int j = 0; j < 4; ++j) {
                const int eid = p[j].x & 0xFFFFF;
                const float* eap = ea + (size_t)eid * ATTR;
                a01[j] = *(const float2*)(eap + 0);
                a23[j] = *(const float2*)(eap + 2);
                a45[j] = *(const float2*)(eap + 4);
                const unsigned short xv16 = xb[(size_t)(unsigned)p[j].y * C_IN + lane];
                const float xv = __uint_as_float((unsigned)xv16 << 16);
                xj[j] = (i + j < cnt) ? xv : 0.f;                 // dup -> 0
            }
#pragma unroll
            for (int j = 0; j < 4; ++j) {
                float s0 = bb[0], s1 = bb[1], s2 = bb[2];
                s0 = fmaf(a01[j].x, w[0][0], s0); s1 = fmaf(a01[j].x, w[0][1], s1); s2 = fmaf(a01[j].x, w[0][2], s2);
                s0 = fmaf(a01[j].y, w[1][0], s0); s1 = fmaf(a01[j].y, w[1][1], s1); s2 = fmaf(a01[j].y, w[1][2], s2);
                s0 = fmaf(a23[j].x, w[2][0], s0); s1 = fmaf(a23[j].x, w[2][1], s1); s2 = fmaf(a23[j].x, w[2][2], s2);
                s0 = fmaf(a23[j].y, w[3][0], s0); s1 = fmaf(a23[j].y, w[3][1], s1); s2 = fmaf(a23[j].y, w[3][2], s2);
                s0 = fmaf(a45[j].x, w[4][0], s0); s1 = fmaf(a45[j].x, w[4][1], s1); s2 = fmaf(a45[j].x, w[4][2], s2);
                s0 = fmaf(a45[j].y, w[5][0], s0); s1 = fmaf(a45[j].y, w[5][1], s1); s2 = fmaf(a45[j].y, w[5][2], s2);
                acc0 = fmaf(fmaxf(s0, 0.f), xj[j], acc0);
                acc1 = fmaf(fmaxf(s1, 0.f), xj[j], acc1);
                acc2 = fmaf(fmaxf(s2, 0.f), xj[j], acc2);
            }
        }
        float* ap = &agg[dl * K3 + col];     // stride-3: 2 lanes/bank = free
        ap[0] = acc0; ap[1] = acc1; ap[2] = acc2;    // plain stores, no atomics
    }
    __syncthreads();

    // Phase C: GEMM from LDS. thread = 4 nodes x 4 outs; k-step 4.
    const int o4 = (t & 31) * 4;
    const int g4 = (t >> 5) * 4;
    float acc[4][4];
#pragma unroll
    for (int i = 0; i < 4; ++i)
#pragma unroll
        for (int j = 0; j < 4; ++j) acc[i][j] = 0.f;

    for (int k = 0; k < K3; k += 4) {
        const float4 w0 = *(const float4*)(Wo + (size_t)(k + 0) * C_OUTC + o4);
        const float4 w1 = *(const float4*)(Wo + (size_t)(k + 1) * C_OUTC + o4);
        const float4 w2 = *(const float4*)(Wo + (size_t)(k + 2) * C_OUTC + o4);
        const float4 w3 = *(const float4*)(Wo + (size_t)(k + 3) * C_OUTC + o4);
#pragma unroll
        for (int i = 0; i < 4; ++i) {
            const float4 av = *(const float4*)(&agg[(g4 + i) * K3 + k]);
            acc[i][0] = fmaf(av.x, w0.x, acc[i][0]);
            acc[i][1] = fmaf(av.x, w0.y, acc[i][1]);
            acc[i][2] = fmaf(av.x, w0.z, acc[i][2]);
            acc[i][3] = fmaf(av.x, w0.w, acc[i][3]);
            acc[i][0] = fmaf(av.y, w1.x, acc[i][0]);
            acc[i][1] = fmaf(av.y, w1.y, acc[i][1]);
            acc[i][2] = fmaf(av.y, w1.z, acc[i][2]);
            acc[i][3] = fmaf(av.y, w1.w, acc[i][3]);
            acc[i][0] = fmaf(av.z, w2.x, acc[i][0]);
            acc[i][1] = fmaf(av.z, w2.y, acc[i][1]);
            acc[i][2] = fmaf(av.z, w2.z, acc[i][2]);
            acc[i][3] = fmaf(av.z, w2.w, acc[i][3]);
            acc[i][0] = fmaf(av.w, w3.x, acc[i][0]);
            acc[i][1] = fmaf(av.w, w3.y, acc[i][1]);
            acc[i][2] = fmaf(av.w, w3.z, acc[i][2]);
            acc[i][3] = fmaf(av.w, w3.w, acc[i][3]);
        }
    }

    const float4 bias = *(const float4*)(bo + o4);
#pragma unroll
    for (int i = 0; i < 4; ++i) {
        const int node = b * 64 + g4 + i;
        if (node < N_NODES) {
            float4 r;
            r.x = tanhf(acc[i][0] + bias.x);
            r.y = tanhf(acc[i][1] + bias.y);
            r.z = tanhf(acc[i][2] + bias.z);
            r.w = tanhf(acc[i][3] + bias.w);
            *(float4*)(out + (size_t)node * (2 * C_OUTC) + l * C_OUTC + o4) = r;
        }
    }
}

extern "C" void kernel_launch(void* const* d_in, const int* in_sizes, int n_in,
                              void* d_out, int out_size, void* d_ws, size_t ws_size,
                              hipStream_t stream) {
    const float* x   = (const float*)d_in[0];
    const int*   ei0 = (const int*)d_in[1];
    const float* ea0 = (const float*)d_in[2];
    const int*   ei1 = (const int*)d_in[3];
    const float* ea1 = (const float*)d_in[4];
    const float* Wi0 = (const float*)d_in[5];
    const float* bi0 = (const float*)d_in[6];
    const float* Wo0 = (const float*)d_in[7];
    const float* bo0 = (const float*)d_in[8];
    const float* Wi1 = (const float*)d_in[9];
    const float* bi1 = (const float*)d_in[10];
    const float* Wo1 = (const float*)d_in[11];
    const float* bo1 = (const float*)d_in[12];
    float* out = (float*)d_out;

    // Workspace (~39.3 MB; >=76.8 MB proven available in R2):
    //   cursor   : 2048 int                        (8 KB)
    //   row_info : 2*NPAD int2                     (800 KB)
    //   xb       : N_NODES*C_IN ushort             (6.4 MB)
    //   seg      : 2*NBK*CAP int2                  (16.0 MB)
    //   csr      : 2*NBK*CAP int2                  (16.0 MB)
    int*  cursor   = (int*)d_ws;
    int2* row_info = (int2*)(cursor + 2048);
    unsigned short* xb = (unsigned short*)(row_info + 2 * NPAD);
    int2* seg      = (int2*)(xb + (size_t)N_NODES * C_IN);
    int2* csr      = seg + (size_t)2 * NBK * CAP;

    hipMemsetAsync(cursor, 0, 2048 * sizeof(int), stream);
    xcvt<<<(N_NODES * C_IN / 4 + 255) / 256, 256, 0, stream>>>(x, xb);
    pass1<<<2 * P1B, 512, 0, stream>>>(ei0, ei1, cursor, seg);
    pass2<<<2 * NBK, 256, 0, stream>>>(cursor, seg, csr, row_info);
    mega<<<2 * NBK, 512, 0, stream>>>(xb, ea0, ea1,
                                      Wi0, bi0, Wo0, bo0,
                                      Wi1, bi1, Wo1, bo1,
                                      row_info, csr, out);
}